// Round 1
// baseline (575.494 us; speedup 1.0000x reference)
//
#include <hip/hip_runtime.h>
#include <hip/hip_bf16.h>

#define B_ 2048
#define D_ 512
#define V_ 50304
#define NCHUNK 131   // 131 chunks * 384 cols = 50304
#define CT_PER 6     // 6 column-tiles of 64 per chunk

typedef __attribute__((ext_vector_type(8))) short short8;
typedef __attribute__((ext_vector_type(4))) float f32x4;

__device__ inline ushort f2bf(float f) {
  unsigned u = __float_as_uint(f);
  u += 0x7fffu + ((u >> 16) & 1u);
  return (ushort)(u >> 16);
}

// ---------------- cast fp32 -> bf16 ----------------
__global__ void cast_kernel(const float* __restrict__ src, ushort* __restrict__ dst, int n4) {
  int i = blockIdx.x * blockDim.x + threadIdx.x;
  int stride = gridDim.x * blockDim.x;
  for (; i < n4; i += stride) {
    float4 f = ((const float4*)src)[i];
    ushort4 o;
    o.x = f2bf(f.x); o.y = f2bf(f.y); o.z = f2bf(f.z); o.w = f2bf(f.w);
    ((ushort4*)dst)[i] = o;
  }
}

// ---------------- exact fp32 target logit ----------------
__global__ void tgt_kernel(const float* __restrict__ sh, const float* __restrict__ sc,
                           const int* __restrict__ targets, float* __restrict__ tgt_out) {
  int gid = blockIdx.x * blockDim.x + threadIdx.x;
  int w = gid >> 6, lane = gid & 63;
  if (w >= B_) return;
  int tgt = targets[w];
  const float4* a = (const float4*)(sh + (size_t)w * D_);
  const float4* b = (const float4*)(sc + (size_t)tgt * D_);
  float acc = 0.f;
#pragma unroll
  for (int i = 0; i < 2; ++i) {
    float4 x = a[lane + i * 64], y = b[lane + i * 64];
    acc += x.x * y.x + x.y * y.y + x.z * y.z + x.w * y.w;
  }
#pragma unroll
  for (int off = 1; off < 64; off <<= 1) acc += __shfl_xor(acc, off);
  if (lane == 0) tgt_out[w] = acc;
}

// ---------------- staging: global (fp32 or bf16) -> swizzled LDS bf16 tile ----------------
template <bool PRE>
__device__ inline void stage_tile(const void* __restrict__ src, int row0, int kk,
                                  short* dst, int tid) {
#pragma unroll
  for (int i = 0; i < 2; ++i) {
    int chunk = i * 256 + tid;        // 0..511
    int row = chunk >> 3;             // 0..63
    int slot = chunk & 7;             // 8 x 8 bf16 slots per row
    int sidx = row * 64 + ((slot ^ (row & 7)) << 3);  // XOR swizzle (G4/T2)
    size_t soff = (size_t)(row0 + row) * D_ + kk * 64 + slot * 8;
    if (PRE) {
      uint4 v = *(const uint4*)((const ushort*)src + soff);
      *(uint4*)(dst + sidx) = v;
    } else {
      const float* p = (const float*)src + soff;
      float4 f0 = *(const float4*)p;
      float4 f1 = *(const float4*)(p + 4);
      ushort o[8];
      o[0] = f2bf(f0.x); o[1] = f2bf(f0.y); o[2] = f2bf(f0.z); o[3] = f2bf(f0.w);
      o[4] = f2bf(f1.x); o[5] = f2bf(f1.y); o[6] = f2bf(f1.z); o[7] = f2bf(f1.w);
      *(uint4*)(dst + sidx) = *(const uint4*)o;
    }
  }
}

// ---------------- fused double-GEMM + online softmax/KL stats ----------------
template <bool PRE>
__global__ __launch_bounds__(256) void lce_main(const void* __restrict__ SH, const void* __restrict__ TH,
                                                const void* __restrict__ SC, const void* __restrict__ TC,
                                                float* __restrict__ partials) {
  __shared__ short lds_sh[64 * 64];
  __shared__ short lds_th[64 * 64];
  __shared__ short lds_sc[64 * 64];
  __shared__ short lds_tc[64 * 64];
  __shared__ float part[2][64][6];
  __shared__ float state[64][5];

  int tid = threadIdx.x;
  int lane = tid & 63, wave = tid >> 6;
  int wr = wave >> 1, wc = wave & 1;
  int row0 = blockIdx.x * 64;
  int ch = blockIdx.y;

  if (tid < 64) {
    state[tid][0] = -1e30f; state[tid][1] = 0.f;
    state[tid][2] = -1e30f; state[tid][3] = 0.f; state[tid][4] = 0.f;
  }

  int rA = lane & 15;
  int kg = lane >> 4;

  for (int ct = 0; ct < CT_PER; ++ct) {
    int c0 = ch * 384 + ct * 64;
    f32x4 as_[2][2], at_[2][2];
#pragma unroll
    for (int mi = 0; mi < 2; ++mi)
#pragma unroll
      for (int ni = 0; ni < 2; ++ni) {
        as_[mi][ni] = (f32x4){0.f, 0.f, 0.f, 0.f};
        at_[mi][ni] = (f32x4){0.f, 0.f, 0.f, 0.f};
      }

    for (int kk = 0; kk < 8; ++kk) {  // K = 512 in steps of 64
      stage_tile<PRE>(SH, row0, kk, lds_sh, tid);
      stage_tile<PRE>(TH, row0, kk, lds_th, tid);
      stage_tile<PRE>(SC, c0, kk, lds_sc, tid);
      stage_tile<PRE>(TC, c0, kk, lds_tc, tid);
      __syncthreads();
#pragma unroll
      for (int ks = 0; ks < 2; ++ks) {
        short8 aS[2], aT[2], bS[2], bT[2];
        int kslot = ks * 4 + kg;
#pragma unroll
        for (int mi = 0; mi < 2; ++mi) {
          int r = wr * 32 + mi * 16 + rA;
          int idx = r * 64 + ((kslot ^ (r & 7)) << 3);
          aS[mi] = *(const short8*)(lds_sh + idx);
          aT[mi] = *(const short8*)(lds_th + idx);
        }
#pragma unroll
        for (int ni = 0; ni < 2; ++ni) {
          int r = wc * 32 + ni * 16 + rA;
          int idx = r * 64 + ((kslot ^ (r & 7)) << 3);
          bS[ni] = *(const short8*)(lds_sc + idx);
          bT[ni] = *(const short8*)(lds_tc + idx);
        }
#pragma unroll
        for (int mi = 0; mi < 2; ++mi)
#pragma unroll
          for (int ni = 0; ni < 2; ++ni) {
            as_[mi][ni] = __builtin_amdgcn_mfma_f32_16x16x32_bf16(aS[mi], bS[ni], as_[mi][ni], 0, 0, 0);
            at_[mi][ni] = __builtin_amdgcn_mfma_f32_16x16x32_bf16(aT[mi], bT[ni], at_[mi][ni], 0, 0, 0);
          }
      }
      __syncthreads();
    }

    // ---- per-column-tile reduction: C/D layout col=lane&15, row=(lane>>4)*4+reg ----
#pragma unroll
    for (int mi = 0; mi < 2; ++mi) {
#pragma unroll
      for (int reg = 0; reg < 4; ++reg) {
        int rloc = wr * 32 + mi * 16 + kg * 4 + reg;
        float sv0 = as_[mi][0][reg], sv1 = as_[mi][1][reg];
        float tv0 = at_[mi][0][reg], tv1 = at_[mi][1][reg];
        float ms = fmaxf(sv0, sv1), mt = fmaxf(tv0, tv1);
#pragma unroll
        for (int off = 1; off < 16; off <<= 1) {
          ms = fmaxf(ms, __shfl_xor(ms, off));
          mt = fmaxf(mt, __shfl_xor(mt, off));
        }
        float e0 = __expf(tv0 - mt), e1 = __expf(tv1 - mt);
        float St = e0 + e1;
        float At = e0 * (tv0 - sv0) + e1 * (tv1 - sv1);
        float Ss = __expf(sv0 - ms) + __expf(sv1 - ms);
#pragma unroll
        for (int off = 1; off < 16; off <<= 1) {
          St += __shfl_xor(St, off);
          At += __shfl_xor(At, off);
          Ss += __shfl_xor(Ss, off);
        }
        if ((lane & 15) == 0) {
          part[wc][rloc][0] = ms; part[wc][rloc][1] = Ss; part[wc][rloc][2] = mt;
          part[wc][rloc][3] = St; part[wc][rloc][4] = At;
        }
      }
    }
    __syncthreads();
    if (tid < 64) {
      float ms0 = part[0][tid][0], Ss0 = part[0][tid][1], mt0 = part[0][tid][2],
            St0 = part[0][tid][3], At0 = part[0][tid][4];
      float ms1 = part[1][tid][0], Ss1 = part[1][tid][1], mt1 = part[1][tid][2],
            St1 = part[1][tid][3], At1 = part[1][tid][4];
      float ms = fmaxf(ms0, ms1);
      float Ss = Ss0 * __expf(ms0 - ms) + Ss1 * __expf(ms1 - ms);
      float mt = fmaxf(mt0, mt1);
      float c0 = __expf(mt0 - mt), c1 = __expf(mt1 - mt);
      float St = St0 * c0 + St1 * c1;
      float At = At0 * c0 + At1 * c1;
      float Ms = state[tid][0], pSs = state[tid][1], Mt = state[tid][2],
            pSt = state[tid][3], pAt = state[tid][4];
      float nms = fmaxf(Ms, ms);
      state[tid][0] = nms;
      state[tid][1] = pSs * __expf(Ms - nms) + Ss * __expf(ms - nms);
      float nmt = fmaxf(Mt, mt);
      float d0 = __expf(Mt - nmt), d1 = __expf(mt - nmt);
      state[tid][2] = nmt;
      state[tid][3] = pSt * d0 + St * d1;
      state[tid][4] = pAt * d0 + At * d1;
    }
    __syncthreads();
  }

  if (tid < 64) {
    float* dst = partials + ((size_t)(row0 + tid) * NCHUNK + ch) * 5;
    dst[0] = state[tid][0]; dst[1] = state[tid][1]; dst[2] = state[tid][2];
    dst[3] = state[tid][3]; dst[4] = state[tid][4];
  }
}

// ---------------- combine chunk partials per row ----------------
__device__ inline void merge5(float& ms, float& Ss, float& mt, float& St, float& At,
                              float ms2, float Ss2, float mt2, float St2, float At2) {
  float nm = fmaxf(ms, ms2);
  Ss = Ss * __expf(ms - nm) + Ss2 * __expf(ms2 - nm);
  ms = nm;
  float nt = fmaxf(mt, mt2);
  float c0 = __expf(mt - nt), c1 = __expf(mt2 - nt);
  St = St * c0 + St2 * c1;
  At = At * c0 + At2 * c1;
  mt = nt;
}

__global__ void combine_kernel(const float* __restrict__ partials, const float* __restrict__ tgt,
                               const float* __restrict__ cec, const float* __restrict__ klc,
                               float* __restrict__ rowvals) {
  int gid = blockIdx.x * blockDim.x + threadIdx.x;
  int w = gid >> 6, lane = gid & 63;
  if (w >= B_) return;
  const float* base = partials + (size_t)w * NCHUNK * 5;
  float ms = -1e30f, Ss = 0.f, mt = -1e30f, St = 0.f, At = 0.f;
  for (int c = lane; c < NCHUNK; c += 64) {
    const float* p = base + c * 5;
    merge5(ms, Ss, mt, St, At, p[0], p[1], p[2], p[3], p[4]);
  }
#pragma unroll
  for (int off = 1; off < 64; off <<= 1) {
    float a = __shfl_xor(ms, off), b = __shfl_xor(Ss, off), c = __shfl_xor(mt, off),
          d = __shfl_xor(St, off), e = __shfl_xor(At, off);
    merge5(ms, Ss, mt, St, At, a, b, c, d, e);
  }
  if (lane == 0) {
    float s_lse = ms + __logf(Ss);
    float t_lse = mt + __logf(St);
    float kl = s_lse - t_lse + At / St;
    float ce = s_lse - tgt[w];
    rowvals[w] = cec[w] * ce + klc[w] * kl;
  }
}

__global__ void final_sum(const float* __restrict__ rowvals, float* __restrict__ out) {
  __shared__ float red[4];
  int tid = threadIdx.x;
  float a = 0.f;
  for (int i = tid; i < B_; i += 256) a += rowvals[i];
#pragma unroll
  for (int off = 1; off < 64; off <<= 1) a += __shfl_xor(a, off);
  if ((tid & 63) == 0) red[tid >> 6] = a;
  __syncthreads();
  if (tid == 0) out[0] = red[0] + red[1] + red[2] + red[3];
}

extern "C" void kernel_launch(void* const* d_in, const int* in_sizes, int n_in,
                              void* d_out, int out_size, void* d_ws, size_t ws_size,
                              hipStream_t stream) {
  const float* sh = (const float*)d_in[0];
  const float* sc = (const float*)d_in[1];
  const float* th = (const float*)d_in[2];
  const float* tc = (const float*)d_in[3];
  const float* cec = (const float*)d_in[4];
  const float* klc = (const float*)d_in[5];
  const int* targets = (const int*)d_in[6];
  float* out = (float*)d_out;

  char* ws = (char*)d_ws;
  size_t off = 0;
  float* partials = (float*)(ws + off); off += (size_t)B_ * NCHUNK * 5 * 4;
  float* tgt = (float*)(ws + off); off += (size_t)B_ * 4;
  float* rowvals = (float*)(ws + off); off += (size_t)B_ * 4;
  size_t cast_off = (off + 255) & ~(size_t)255;
  size_t cbytes = ((size_t)V_ * D_ * 2) * 2 + ((size_t)B_ * D_ * 2) * 2;
  bool pre = (ws_size >= cast_off + cbytes);

  if (pre) {
    ushort* shb = (ushort*)(ws + cast_off);
    ushort* thb = shb + (size_t)B_ * D_;
    ushort* scb = thb + (size_t)B_ * D_;
    ushort* tcb = scb + (size_t)V_ * D_;
    cast_kernel<<<1024, 256, 0, stream>>>(sh, shb, B_ * D_ / 4);
    cast_kernel<<<1024, 256, 0, stream>>>(th, thb, B_ * D_ / 4);
    cast_kernel<<<4096, 256, 0, stream>>>(sc, scb, V_ * D_ / 4);
    cast_kernel<<<4096, 256, 0, stream>>>(tc, tcb, V_ * D_ / 4);
    tgt_kernel<<<512, 256, 0, stream>>>(sh, sc, targets, tgt);
    dim3 grid(B_ / 64, NCHUNK);
    lce_main<true><<<grid, 256, 0, stream>>>(shb, thb, scb, tcb, partials);
  } else {
    tgt_kernel<<<512, 256, 0, stream>>>(sh, sc, targets, tgt);
    dim3 grid(B_ / 64, NCHUNK);
    lce_main<false><<<grid, 256, 0, stream>>>(sh, th, sc, tc, partials);
  }
  combine_kernel<<<512, 256, 0, stream>>>(partials, tgt, cec, klc, rowvals);
  final_sum<<<1, 256, 0, stream>>>(rowvals, out);
}

// Round 2
// 431.026 us; speedup vs baseline: 1.3352x; 1.3352x over previous
//
#include <hip/hip_runtime.h>
#include <hip/hip_bf16.h>

#define B_ 2048
#define D_ 512
#define V_ 50304
#define NCB 393   // 393 col-blocks * 128 = 50304
#define LOG2E 1.44269504088896340736f
#define LN2 0.69314718055994530942f

typedef __attribute__((ext_vector_type(8))) short short8;
typedef __attribute__((ext_vector_type(4))) float f32x4;

__device__ inline ushort f2bf(float f) {
  unsigned u = __float_as_uint(f);
  u += 0x7fffu + ((u >> 16) & 1u);
  return (ushort)(u >> 16);
}

// ---------------- exact fp32 target logit (one wave per row) ----------------
__global__ void tgt_kernel(const float* __restrict__ sh, const float* __restrict__ sc,
                           const int* __restrict__ targets, float* __restrict__ tgt_out) {
  int gid = blockIdx.x * blockDim.x + threadIdx.x;
  int w = gid >> 6, lane = gid & 63;
  if (w >= B_) return;
  int tgt = targets[w];
  const float4* a = (const float4*)(sh + (size_t)w * D_);
  const float4* b = (const float4*)(sc + (size_t)tgt * D_);
  float acc = 0.f;
#pragma unroll
  for (int i = 0; i < 2; ++i) {
    float4 x = a[lane + i * 64], y = b[lane + i * 64];
    acc += x.x * y.x + x.y * y.y + x.z * y.z + x.w * y.w;
  }
#pragma unroll
  for (int off = 1; off < 64; off <<= 1) acc += __shfl_xor(acc, off);
  if (lane == 0) tgt_out[w] = acc;
}

// ---------------- fused dual-GEMM (128x128 tile) + no-max exp2 stats ----------------
// Hidden states are scaled by log2e during staging, so exp(logit) == exp2(tile value).
__global__ __launch_bounds__(256, 2) void lce_main(
    const float* __restrict__ SH, const float* __restrict__ TH,
    const float* __restrict__ SC, const float* __restrict__ TC,
    float* __restrict__ stats) {
  __shared__ __align__(16) short lds[4][128][64];  // 64 KB: SH, TH, SC, TC tiles

  const int tid = threadIdx.x;
  const int lane = tid & 63, w = tid >> 6;
  const int wr = w >> 1, wc = w & 1;
  const int row0 = blockIdx.x * 128;  // rows into B_
  const int col0 = blockIdx.y * 128;  // rows into V_ (B^T layout)

  f32x4 accS[4][4], accT[4][4];
#pragma unroll
  for (int i = 0; i < 4; ++i)
#pragma unroll
    for (int j = 0; j < 4; ++j) {
      accS[i][j] = (f32x4){0.f, 0.f, 0.f, 0.f};
      accT[i][j] = (f32x4){0.f, 0.f, 0.f, 0.f};
    }

  // staging geometry: each thread owns 16B (8 bf16) per chunk; 4 chunks per tile
  const int rit0 = w * 32 + (lane >> 3);             // tile row (+c*8)
  const int scol = ((lane & 7) ^ (lane >> 3)) << 3;  // swizzled source col (elements)
  const int dslot = (lane & 7) << 3;                 // linear dest col (elements)

  const float* bases[4] = {SH + (size_t)(row0 + rit0) * D_ + scol,
                           TH + (size_t)(row0 + rit0) * D_ + scol,
                           SC + (size_t)(col0 + rit0) * D_ + scol,
                           TC + (size_t)(col0 + rit0) * D_ + scol};

  const int rA = lane & 15;
  const int kg = lane >> 4;

  for (int kk = 0; kk < 8; ++kk) {  // K = 512 in steps of 64
    if (kk) __syncthreads();
#pragma unroll
    for (int t = 0; t < 4; ++t) {
#pragma unroll
      for (int c = 0; c < 4; ++c) {
        const float* p = bases[t] + (size_t)(c * 8) * D_ + kk * 64;
        float4 f0 = *(const float4*)p;
        float4 f1 = *(const float4*)(p + 4);
        if (t < 2) {  // scale hidden states by log2(e); compile-time branch
          f0.x *= LOG2E; f0.y *= LOG2E; f0.z *= LOG2E; f0.w *= LOG2E;
          f1.x *= LOG2E; f1.y *= LOG2E; f1.z *= LOG2E; f1.w *= LOG2E;
        }
        ushort o[8];
        o[0] = f2bf(f0.x); o[1] = f2bf(f0.y); o[2] = f2bf(f0.z); o[3] = f2bf(f0.w);
        o[4] = f2bf(f1.x); o[5] = f2bf(f1.y); o[6] = f2bf(f1.z); o[7] = f2bf(f1.w);
        *(uint4*)&lds[t][rit0 + c * 8][dslot] = *(const uint4*)o;
      }
    }
    __syncthreads();

#pragma unroll
    for (int ks = 0; ks < 2; ++ks) {
      const int kslot = ks * 4 + kg;
      const int koff = (kslot ^ (lane & 7)) << 3;  // swizzled k-slot (row&7 == lane&7 here)
      short8 a[4], b[4];
      // ---- student ----
#pragma unroll
      for (int mi = 0; mi < 4; ++mi) a[mi] = *(const short8*)&lds[0][wr * 64 + mi * 16 + rA][koff];
#pragma unroll
      for (int ni = 0; ni < 4; ++ni) b[ni] = *(const short8*)&lds[2][wc * 64 + ni * 16 + rA][koff];
#pragma unroll
      for (int mi = 0; mi < 4; ++mi)
#pragma unroll
        for (int ni = 0; ni < 4; ++ni)
          accS[mi][ni] = __builtin_amdgcn_mfma_f32_16x16x32_bf16(a[mi], b[ni], accS[mi][ni], 0, 0, 0);
      // ---- teacher ----
#pragma unroll
      for (int mi = 0; mi < 4; ++mi) a[mi] = *(const short8*)&lds[1][wr * 64 + mi * 16 + rA][koff];
#pragma unroll
      for (int ni = 0; ni < 4; ++ni) b[ni] = *(const short8*)&lds[3][wc * 64 + ni * 16 + rA][koff];
#pragma unroll
      for (int mi = 0; mi < 4; ++mi)
#pragma unroll
        for (int ni = 0; ni < 4; ++ni)
          accT[mi][ni] = __builtin_amdgcn_mfma_f32_16x16x32_bf16(a[mi], b[ni], accT[mi][ni], 0, 0, 0);
    }
  }
  __syncthreads();

  // ---------------- epilogue: per-row Ss, St, At (log2 units), no max needed ----------------
  float* sbuf = (float*)lds;  // alias tile LDS: [128 rows][2 wc][4]
#pragma unroll
  for (int mi = 0; mi < 4; ++mi) {
#pragma unroll
    for (int reg = 0; reg < 4; ++reg) {
      float ss = 0.f, st = 0.f, at = 0.f;
#pragma unroll
      for (int ni = 0; ni < 4; ++ni) {
        float sv = accS[mi][ni][reg], tv = accT[mi][ni][reg];
        float es = __builtin_amdgcn_exp2f(sv);
        float et = __builtin_amdgcn_exp2f(tv);
        ss += es;
        st += et;
        at += et * (tv - sv);
      }
#pragma unroll
      for (int off = 1; off < 16; off <<= 1) {
        ss += __shfl_xor(ss, off);
        st += __shfl_xor(st, off);
        at += __shfl_xor(at, off);
      }
      if ((lane & 15) == 0) {
        int row = wr * 64 + mi * 16 + kg * 4 + reg;
        float* d = sbuf + (row * 2 + wc) * 4;
        d[0] = ss; d[1] = st; d[2] = at;
      }
    }
  }
  __syncthreads();
  if (tid < 128) {
    float ss = sbuf[(tid * 2) * 4 + 0] + sbuf[(tid * 2 + 1) * 4 + 0];
    float st = sbuf[(tid * 2) * 4 + 1] + sbuf[(tid * 2 + 1) * 4 + 1];
    float at = sbuf[(tid * 2) * 4 + 2] + sbuf[(tid * 2 + 1) * 4 + 2];
    float* g = stats + (size_t)(row0 + tid) * 3;
    atomicAdd(g + 0, ss);
    atomicAdd(g + 1, st);
    atomicAdd(g + 2, at);
  }
}

// ---------------- finalize: per-row loss + global sum ----------------
__global__ void finalize(const float* __restrict__ stats, const float* __restrict__ tgt,
                         const float* __restrict__ cec, const float* __restrict__ klc,
                         float* __restrict__ out) {
  __shared__ float red[16];
  int tid = threadIdx.x;  // 1024 threads
  float acc = 0.f;
  for (int r = tid; r < B_; r += 1024) {
    float ss = stats[r * 3 + 0], st = stats[r * 3 + 1], at = stats[r * 3 + 2];
    float s_lse = LN2 * __builtin_amdgcn_logf(ss);
    float t_lse = LN2 * __builtin_amdgcn_logf(st);
    float kl = s_lse - t_lse + LN2 * at / st;
    float ce = s_lse - tgt[r];
    acc += cec[r] * ce + klc[r] * kl;
  }
#pragma unroll
  for (int off = 1; off < 64; off <<= 1) acc += __shfl_xor(acc, off);
  if ((tid & 63) == 0) red[tid >> 6] = acc;
  __syncthreads();
  if (tid == 0) {
    float s = 0.f;
#pragma unroll
    for (int i = 0; i < 16; ++i) s += red[i];
    out[0] = s;
  }
}

extern "C" void kernel_launch(void* const* d_in, const int* in_sizes, int n_in,
                              void* d_out, int out_size, void* d_ws, size_t ws_size,
                              hipStream_t stream) {
  const float* sh = (const float*)d_in[0];
  const float* sc = (const float*)d_in[1];
  const float* th = (const float*)d_in[2];
  const float* tc = (const float*)d_in[3];
  const float* cec = (const float*)d_in[4];
  const float* klc = (const float*)d_in[5];
  const int* targets = (const int*)d_in[6];
  float* out = (float*)d_out;

  char* ws = (char*)d_ws;
  float* stats = (float*)ws;                 // [2048][3]
  float* tgt = (float*)(ws + 32768);         // [2048]

  hipMemsetAsync(stats, 0, (size_t)B_ * 3 * sizeof(float), stream);
  tgt_kernel<<<512, 256, 0, stream>>>(sh, sc, targets, tgt);
  dim3 grid(B_ / 128, NCB);
  lce_main<<<grid, 256, 0, stream>>>(sh, th, sc, tc, stats);
  finalize<<<1, 1024, 0, stream>>>(stats, tgt, cec, klc, out);
}

// Round 3
// 321.892 us; speedup vs baseline: 1.7878x; 1.3390x over previous
//
#include <hip/hip_runtime.h>
#include <hip/hip_bf16.h>

#define B_ 2048
#define D_ 512
#define V_ 50304
#define NCB 393   // 393 col-blocks * 128 = 50304
#define LOG2E 1.44269504088896340736f
#define LN2 0.69314718055994530942f

typedef __attribute__((ext_vector_type(8))) short short8;
typedef __attribute__((ext_vector_type(4))) float f32x4;

__device__ inline ushort f2bf(float f) {
  unsigned u = __float_as_uint(f);
  u += 0x7fffu + ((u >> 16) & 1u);
  return (ushort)(u >> 16);
}

__device__ inline void gload16(const void* g, void* l) {
  __builtin_amdgcn_global_load_lds((const __attribute__((address_space(1))) void*)g,
                                   (__attribute__((address_space(3))) void*)l, 16, 0, 0);
}

// ---------------- cast fp32 -> bf16 (optionally x log2e) ----------------
template <bool SCALE>
__global__ void cast_kernel(const float* __restrict__ src, ushort* __restrict__ dst, int n4) {
  int i = blockIdx.x * blockDim.x + threadIdx.x;
  int stride = gridDim.x * blockDim.x;
  for (; i < n4; i += stride) {
    float4 f = ((const float4*)src)[i];
    if (SCALE) { f.x *= LOG2E; f.y *= LOG2E; f.z *= LOG2E; f.w *= LOG2E; }
    ushort4 o;
    o.x = f2bf(f.x); o.y = f2bf(f.y); o.z = f2bf(f.z); o.w = f2bf(f.w);
    ((ushort4*)dst)[i] = o;
  }
}

// ---------------- exact fp32 target logit (one wave per row) ----------------
__global__ void tgt_kernel(const float* __restrict__ sh, const float* __restrict__ sc,
                           const int* __restrict__ targets, float* __restrict__ tgt_out) {
  int gid = blockIdx.x * blockDim.x + threadIdx.x;
  int w = gid >> 6, lane = gid & 63;
  if (w >= B_) return;
  int tgt = targets[w];
  const float4* a = (const float4*)(sh + (size_t)w * D_);
  const float4* b = (const float4*)(sc + (size_t)tgt * D_);
  float acc = 0.f;
#pragma unroll
  for (int i = 0; i < 2; ++i) {
    float4 x = a[lane + i * 64], y = b[lane + i * 64];
    acc += x.x * y.x + x.y * y.y + x.z * y.z + x.w * y.w;
  }
#pragma unroll
  for (int off = 1; off < 64; off <<= 1) acc += __shfl_xor(acc, off);
  if (lane == 0) tgt_out[w] = acc;
}

// ---------------- fused dual-GEMM (128x128) + no-max exp2 stats ----------------
// Hidden states pre-scaled by log2e in bf16; classifiers bf16 (tiered) or fp32.
template <bool SCP, bool TCP>
__global__ __launch_bounds__(256, 2) void lce_main(
    const ushort* __restrict__ SHb, const ushort* __restrict__ THb,
    const void* __restrict__ SCp, const void* __restrict__ TCp,
    float* __restrict__ stats) {
  __shared__ __align__(16) short lds[4][128][64];  // 64 KB: SH, TH, SC, TC tiles

  const int tid = threadIdx.x;
  const int lane = tid & 63, w = tid >> 6;
  const int wr = w >> 1, wc = w & 1;
  const int row0 = blockIdx.x * 128;
  const int col0 = blockIdx.y * 128;

  const int lr = lane >> 3;                 // row-within-8
  const int swz8 = ((lane & 7) ^ lr) * 8;   // pre-swizzled source slot (elements)

  // per-lane global bases (element offsets); all staged row bases are == 0 mod 8
  const ushort* gSH = SHb + (size_t)(row0 + w * 32 + lr) * D_ + swz8;
  const ushort* gTH = THb + (size_t)(row0 + w * 32 + lr) * D_ + swz8;
  const ushort* gSCb = nullptr; const float* gSCf = nullptr;
  const ushort* gTCb = nullptr; const float* gTCf = nullptr;
  if constexpr (SCP) gSCb = (const ushort*)SCp + (size_t)(col0 + w * 32 + lr) * D_ + swz8;
  else               gSCf = (const float*)SCp + (size_t)(col0 + w * 32 + lr) * D_ + swz8;
  if constexpr (TCP) gTCb = (const ushort*)TCp + (size_t)(col0 + w * 32 + lr) * D_ + swz8;
  else               gTCf = (const float*)TCp + (size_t)(col0 + w * 32 + lr) * D_ + swz8;

  f32x4 accS[4][4], accT[4][4];
#pragma unroll
  for (int i = 0; i < 4; ++i)
#pragma unroll
    for (int j = 0; j < 4; ++j) {
      accS[i][j] = (f32x4){0.f, 0.f, 0.f, 0.f};
      accT[i][j] = (f32x4){0.f, 0.f, 0.f, 0.f};
    }

  auto stage_f32 = [&](const float* gf, int t, int kk) {
#pragma unroll
    for (int i = 0; i < 4; ++i) {
      const float* p = gf + i * 8 * D_ + kk * 64;
      float4 f0 = *(const float4*)p;
      float4 f1 = *(const float4*)(p + 4);
      ushort o[8];
      o[0] = f2bf(f0.x); o[1] = f2bf(f0.y); o[2] = f2bf(f0.z); o[3] = f2bf(f0.w);
      o[4] = f2bf(f1.x); o[5] = f2bf(f1.y); o[6] = f2bf(f1.z); o[7] = f2bf(f1.w);
      *(uint4*)&lds[t][w * 32 + i * 8 + lr][(lane & 7) * 8] = *(const uint4*)o;
    }
  };

  const int rA = lane & 15;
  const int kg = lane >> 4;

  for (int kk = 0; kk < 8; ++kk) {  // K = 512 in steps of 64
    if (kk) __syncthreads();
#pragma unroll
    for (int i = 0; i < 4; ++i) {
      gload16(gSH + i * 8 * D_ + kk * 64, &lds[0][w * 32 + i * 8][0]);
      gload16(gTH + i * 8 * D_ + kk * 64, &lds[1][w * 32 + i * 8][0]);
    }
    if constexpr (SCP) {
#pragma unroll
      for (int i = 0; i < 4; ++i) gload16(gSCb + i * 8 * D_ + kk * 64, &lds[2][w * 32 + i * 8][0]);
    } else {
      stage_f32(gSCf, 2, kk);
    }
    if constexpr (TCP) {
#pragma unroll
      for (int i = 0; i < 4; ++i) gload16(gTCb + i * 8 * D_ + kk * 64, &lds[3][w * 32 + i * 8][0]);
    } else {
      stage_f32(gTCf, 3, kk);
    }
    __syncthreads();

#pragma unroll
    for (int ks = 0; ks < 2; ++ks) {
      const int kslot = ks * 4 + kg;
      const int koff = (kslot ^ (lane & 7)) << 3;  // read-side swizzle
      short8 a[4], b[4];
      // ---- student ----
#pragma unroll
      for (int mi = 0; mi < 4; ++mi) a[mi] = *(const short8*)&lds[0][wr * 64 + mi * 16 + rA][koff];
#pragma unroll
      for (int ni = 0; ni < 4; ++ni) b[ni] = *(const short8*)&lds[2][wc * 64 + ni * 16 + rA][koff];
#pragma unroll
      for (int mi = 0; mi < 4; ++mi)
#pragma unroll
        for (int ni = 0; ni < 4; ++ni)
          accS[mi][ni] = __builtin_amdgcn_mfma_f32_16x16x32_bf16(a[mi], b[ni], accS[mi][ni], 0, 0, 0);
      // ---- teacher ----
#pragma unroll
      for (int mi = 0; mi < 4; ++mi) a[mi] = *(const short8*)&lds[1][wr * 64 + mi * 16 + rA][koff];
#pragma unroll
      for (int ni = 0; ni < 4; ++ni) b[ni] = *(const short8*)&lds[3][wc * 64 + ni * 16 + rA][koff];
#pragma unroll
      for (int mi = 0; mi < 4; ++mi)
#pragma unroll
        for (int ni = 0; ni < 4; ++ni)
          accT[mi][ni] = __builtin_amdgcn_mfma_f32_16x16x32_bf16(a[mi], b[ni], accT[mi][ni], 0, 0, 0);
    }
  }
  __syncthreads();

  // ---------------- epilogue: per-row Ss, St, At (log2 units) ----------------
  float* sbuf = (float*)lds;  // alias tile LDS: [128 rows][2 wc][4]
#pragma unroll
  for (int mi = 0; mi < 4; ++mi) {
#pragma unroll
    for (int reg = 0; reg < 4; ++reg) {
      float ss = 0.f, st = 0.f, at = 0.f;
#pragma unroll
      for (int ni = 0; ni < 4; ++ni) {
        float sv = accS[mi][ni][reg], tv = accT[mi][ni][reg];
        float es = __builtin_amdgcn_exp2f(sv);
        float et = __builtin_amdgcn_exp2f(tv);
        ss += es;
        st += et;
        at += et * (tv - sv);
      }
#pragma unroll
      for (int off = 1; off < 16; off <<= 1) {
        ss += __shfl_xor(ss, off);
        st += __shfl_xor(st, off);
        at += __shfl_xor(at, off);
      }
      if ((lane & 15) == 0) {
        int row = wr * 64 + mi * 16 + kg * 4 + reg;
        float* d = sbuf + (row * 2 + wc) * 4;
        d[0] = ss; d[1] = st; d[2] = at;
      }
    }
  }
  __syncthreads();
  if (tid < 128) {
    float ss = sbuf[(tid * 2) * 4 + 0] + sbuf[(tid * 2 + 1) * 4 + 0];
    float st = sbuf[(tid * 2) * 4 + 1] + sbuf[(tid * 2 + 1) * 4 + 1];
    float at = sbuf[(tid * 2) * 4 + 2] + sbuf[(tid * 2 + 1) * 4 + 2];
    float* g = stats + (size_t)(row0 + tid) * 3;
    atomicAdd(g + 0, ss);
    atomicAdd(g + 1, st);
    atomicAdd(g + 2, at);
  }
}

// ---------------- finalize: per-row loss + global sum ----------------
__global__ void finalize(const float* __restrict__ stats, const float* __restrict__ tgt,
                         const float* __restrict__ cec, const float* __restrict__ klc,
                         float* __restrict__ out) {
  __shared__ float red[16];
  int tid = threadIdx.x;  // 1024 threads
  float acc = 0.f;
  for (int r = tid; r < B_; r += 1024) {
    float ss = stats[r * 3 + 0], st = stats[r * 3 + 1], at = stats[r * 3 + 2];
    float s_lse = LN2 * __builtin_amdgcn_logf(ss);
    float t_lse = LN2 * __builtin_amdgcn_logf(st);
    float kl = s_lse - t_lse + LN2 * at / st;
    float ce = s_lse - tgt[r];
    acc += cec[r] * ce + klc[r] * kl;
  }
#pragma unroll
  for (int off = 1; off < 64; off <<= 1) acc += __shfl_xor(acc, off);
  if ((tid & 63) == 0) red[tid >> 6] = acc;
  __syncthreads();
  if (tid == 0) {
    float s = 0.f;
#pragma unroll
    for (int i = 0; i < 16; ++i) s += red[i];
    out[0] = s;
  }
}

extern "C" void kernel_launch(void* const* d_in, const int* in_sizes, int n_in,
                              void* d_out, int out_size, void* d_ws, size_t ws_size,
                              hipStream_t stream) {
  const float* sh = (const float*)d_in[0];
  const float* sc = (const float*)d_in[1];
  const float* th = (const float*)d_in[2];
  const float* tc = (const float*)d_in[3];
  const float* cec = (const float*)d_in[4];
  const float* klc = (const float*)d_in[5];
  const int* targets = (const int*)d_in[6];
  float* out = (float*)d_out;

  char* ws = (char*)d_ws;
  float* stats = (float*)ws;                       // 24 KB: [2048][3]
  float* tgt = (float*)(ws + 24576);               // 8 KB
  ushort* SHb = (ushort*)(ws + 32768);             // 2 MB
  ushort* THb = SHb + (size_t)B_ * D_;             // 2 MB
  size_t off1 = 32768 + (size_t)B_ * D_ * 2 * 2;   // 4,227,072
  ushort* SCb = (ushort*)(ws + off1);
  size_t scb = (size_t)V_ * D_ * 2;                // 51,511,296
  ushort* TCb = (ushort*)(ws + off1 + scb);
  bool scp = ws_size >= off1 + scb;                // >= 55.7 MB
  bool tcp = ws_size >= off1 + 2 * scb;            // >= 107.3 MB

  hipMemsetAsync(stats, 0, 24576, stream);
  cast_kernel<true><<<512, 256, 0, stream>>>(sh, SHb, B_ * D_ / 4);
  cast_kernel<true><<<512, 256, 0, stream>>>(th, THb, B_ * D_ / 4);
  if (scp) cast_kernel<false><<<4096, 256, 0, stream>>>(sc, SCb, V_ * D_ / 4);
  if (tcp) cast_kernel<false><<<4096, 256, 0, stream>>>(tc, TCb, V_ * D_ / 4);
  tgt_kernel<<<512, 256, 0, stream>>>(sh, sc, targets, tgt);

  dim3 grid(B_ / 128, NCB);
  if (scp && tcp)
    lce_main<true, true><<<grid, 256, 0, stream>>>(SHb, THb, SCb, TCb, stats);
  else if (scp)
    lce_main<true, false><<<grid, 256, 0, stream>>>(SHb, THb, SCb, tc, stats);
  else
    lce_main<false, false><<<grid, 256, 0, stream>>>(SHb, THb, sc, tc, stats);

  finalize<<<1, 1024, 0, stream>>>(stats, tgt, cec, klc, out);
}

// Round 4
// 268.853 us; speedup vs baseline: 2.1406x; 1.1973x over previous
//
#include <hip/hip_runtime.h>
#include <hip/hip_fp8.h>

#define B_ 2048
#define D_ 512
#define V_ 50304
#define NROWB 16            // 2048 / 128
#define NCOLB 393           // 50304 / 128
#define NWG (NROWB * NCOLB) // 6288 = 8 * 786
#define LOG2E 1.44269504088896340736f
#define LN2 0.69314718055994530942f

typedef __attribute__((ext_vector_type(4))) float f32x4;
typedef __attribute__((ext_vector_type(2))) unsigned long ulx2;
typedef unsigned char u8;

__device__ inline void gload16(const void* g, void* l) {
  __builtin_amdgcn_global_load_lds((const __attribute__((address_space(1))) void*)g,
                                   (__attribute__((address_space(3))) void*)l, 16, 0, 0);
}

// ---------------- cast fp32 -> fp8 e4m3 (scaled) ----------------
__global__ void cast8_kernel(const float* __restrict__ src, uint2* __restrict__ dst,
                             float scale, int n8) {
  int i = blockIdx.x * blockDim.x + threadIdx.x;
  int stride = gridDim.x * blockDim.x;
  const float4* s4 = (const float4*)src;
  for (; i < n8; i += stride) {
    float4 a = s4[2 * i], b = s4[2 * i + 1];
    union { u8 c[8]; uint2 u; } p;
    p.c[0] = __hip_fp8_e4m3(a.x * scale).__x;
    p.c[1] = __hip_fp8_e4m3(a.y * scale).__x;
    p.c[2] = __hip_fp8_e4m3(a.z * scale).__x;
    p.c[3] = __hip_fp8_e4m3(a.w * scale).__x;
    p.c[4] = __hip_fp8_e4m3(b.x * scale).__x;
    p.c[5] = __hip_fp8_e4m3(b.y * scale).__x;
    p.c[6] = __hip_fp8_e4m3(b.z * scale).__x;
    p.c[7] = __hip_fp8_e4m3(b.w * scale).__x;
    dst[i] = p.u;
  }
}

// ---------------- exact fp32 target logit (one wave per row) ----------------
__global__ void tgt_kernel(const float* __restrict__ sh, const float* __restrict__ sc,
                           const int* __restrict__ targets, float* __restrict__ tgt_out) {
  int gid = blockIdx.x * blockDim.x + threadIdx.x;
  int w = gid >> 6, lane = gid & 63;
  if (w >= B_) return;
  int tgt = targets[w];
  const float4* a = (const float4*)(sh + (size_t)w * D_);
  const float4* b = (const float4*)(sc + (size_t)tgt * D_);
  float acc = 0.f;
#pragma unroll
  for (int i = 0; i < 2; ++i) {
    float4 x = a[lane + i * 64], y = b[lane + i * 64];
    acc += x.x * y.x + x.y * y.y + x.z * y.z + x.w * y.w;
  }
#pragma unroll
  for (int off = 1; off < 64; off <<= 1) acc += __shfl_xor(acc, off);
  if (lane == 0) tgt_out[w] = acc;
}

// ---------------- fused dual-GEMM fp8, S/T wave split, counted-vmcnt pipeline ----------------
// smem: [buf][mat][row][128] fp8, 64 KB. A-frags live in registers (global L2-hot).
__global__ __launch_bounds__(256, 2) void lce_main(
    const u8* __restrict__ SH8, const u8* __restrict__ TH8,
    const u8* __restrict__ SC8, const u8* __restrict__ TC8,
    float* __restrict__ stats) {
  __shared__ __align__(16) u8 smem[2][2][128][128];

  const int tid = threadIdx.x;
  const int lane = tid & 63, w = tid >> 6;
  const int mat = w & 1;        // 0 = student, 1 = teacher
  const int wr = w >> 1;        // row half (64 rows)
  const int rA = lane & 15;
  const int kg = lane >> 4;     // 0..3
  const int r7 = rA & 7;

  // XCD-aware bijective swizzle: 6288 = 8 * 786
  int hw = blockIdx.x;
  int lid = (hw & 7) * 786 + (hw >> 3);
  const int row0 = (lid & 15) * 128;
  const int col0 = (lid >> 4) * 128;

  // ---- staging geometry (B-panels SC/TC -> LDS, linear dest + pre-swizzled src) ----
  const int srow_lo = (lane >> 3);           // row within 8-row group
  const int sq = ((lane & 7) ^ srow_lo) * 16;  // swizzled source quad byte
  const u8* gB[2] = {SC8 + (size_t)(col0 + w * 32 + srow_lo) * D_ + sq,
                     TC8 + (size_t)(col0 + w * 32 + srow_lo) * D_ + sq};

  // ---- A (hidden) per-lane global base: rows row0+wr*64+rA(+mi*16), 16B at kg*16 ----
  const u8* gA = (mat ? TH8 : SH8) + (size_t)(row0 + wr * 64 + rA) * D_ + kg * 16;

  f32x4 acc[4][8];
#pragma unroll
  for (int i = 0; i < 4; ++i)
#pragma unroll
    for (int j = 0; j < 8; ++j) acc[i][j] = (f32x4){0.f, 0.f, 0.f, 0.f};

  ulx2 afr[2][2][4];  // [kk parity][hp][mi]

#define STAGE(buf, kk)                                                        \
  {                                                                           \
    _Pragma("unroll") for (int t = 0; t < 2; ++t) {                           \
      _Pragma("unroll") for (int i = 0; i < 4; ++i) {                         \
        gload16(gB[t] + (size_t)(i * 8) * D_ + (kk) * 128,                    \
                &smem[buf][t][w * 32 + i * 8][0]);                            \
      }                                                                       \
    }                                                                         \
  }

#define LOADA(par, kk)                                                        \
  {                                                                           \
    _Pragma("unroll") for (int mi = 0; mi < 4; ++mi) {                        \
      const u8* p = gA + (size_t)(mi * 16) * D_ + (kk) * 128;                 \
      afr[par][0][mi] = *(const ulx2*)p;                                      \
      afr[par][1][mi] = *(const ulx2*)(p + 64);                               \
    }                                                                         \
  }

  // prologue
  STAGE(0, 0);
  LOADA(0, 0);

#pragma unroll
  for (int kk = 0; kk < 4; ++kk) {
    const int par = kk & 1;
    if (kk < 3) {
      STAGE(par ^ 1, kk + 1);
      LOADA(par ^ 1, kk + 1);
    }
    if (kk < 3)
      asm volatile("s_waitcnt vmcnt(16)\n\ts_barrier" ::: "memory");
    else
      asm volatile("s_waitcnt vmcnt(8)\n\ts_barrier" ::: "memory");

#pragma unroll
    for (int hp = 0; hp < 2; ++hp) {
      ulx2 bfr[8];
#pragma unroll
      for (int ni = 0; ni < 8; ++ni)
        bfr[ni] = *(const ulx2*)&smem[par][mat][ni * 16 + rA][((hp * 4 + kg) ^ r7) * 16];
      __builtin_amdgcn_s_setprio(1);
#pragma unroll
      for (int mi = 0; mi < 4; ++mi)
#pragma unroll
        for (int ni = 0; ni < 8; ++ni) {
          acc[mi][ni] = __builtin_amdgcn_mfma_f32_16x16x32_fp8_fp8(
              (long)afr[par][hp][mi].x, (long)bfr[ni].x, acc[mi][ni], 0, 0, 0);
          acc[mi][ni] = __builtin_amdgcn_mfma_f32_16x16x32_fp8_fp8(
              (long)afr[par][hp][mi].y, (long)bfr[ni].y, acc[mi][ni], 0, 0, 0);
        }
      __builtin_amdgcn_s_setprio(0);
    }
    asm volatile("s_barrier" ::: "memory");
  }

  // ---------------- epilogue ----------------
  const float inv = 1.0f / 256.0f;  // descale: acc = logit * 256 * LOG2E
  float2* exch = (float2*)smem;     // [wr][mi][ni][rp][lane] float2 = 64 KB

  if (mat == 0) {
#pragma unroll
    for (int mi = 0; mi < 4; ++mi)
#pragma unroll
      for (int ni = 0; ni < 8; ++ni)
#pragma unroll
        for (int rp = 0; rp < 2; ++rp) {
          float2 v = make_float2(acc[mi][ni][2 * rp] * inv, acc[mi][ni][2 * rp + 1] * inv);
          exch[(size_t)((((wr * 4 + mi) * 8 + ni) * 2 + rp) * 64 + lane)] = v;
        }
  }
  asm volatile("s_waitcnt lgkmcnt(0)\n\ts_barrier" ::: "memory");

  if (mat == 0) {
#pragma unroll
    for (int mi = 0; mi < 4; ++mi) {
      float ssr[4] = {0.f, 0.f, 0.f, 0.f};
#pragma unroll
      for (int ni = 0; ni < 8; ++ni)
#pragma unroll
        for (int reg = 0; reg < 4; ++reg)
          ssr[reg] += __builtin_amdgcn_exp2f(acc[mi][ni][reg] * inv);
#pragma unroll
      for (int reg = 0; reg < 4; ++reg) {
        float v = ssr[reg];
#pragma unroll
        for (int off = 1; off < 16; off <<= 1) v += __shfl_xor(v, off);
        if (rA == 0)
          atomicAdd(&stats[(size_t)(row0 + wr * 64 + mi * 16 + kg * 4 + reg) * 3 + 0], v);
      }
    }
  } else {
#pragma unroll
    for (int mi = 0; mi < 4; ++mi) {
      float str[4] = {0.f, 0.f, 0.f, 0.f};
      float atr[4] = {0.f, 0.f, 0.f, 0.f};
#pragma unroll
      for (int ni = 0; ni < 8; ++ni)
#pragma unroll
        for (int rp = 0; rp < 2; ++rp) {
          float2 sv = exch[(size_t)((((wr * 4 + mi) * 8 + ni) * 2 + rp) * 64 + lane)];
          float tv0 = acc[mi][ni][2 * rp] * inv;
          float tv1 = acc[mi][ni][2 * rp + 1] * inv;
          float et0 = __builtin_amdgcn_exp2f(tv0);
          float et1 = __builtin_amdgcn_exp2f(tv1);
          str[2 * rp] += et0;
          str[2 * rp + 1] += et1;
          atr[2 * rp] += et0 * (tv0 - sv.x);
          atr[2 * rp + 1] += et1 * (tv1 - sv.y);
        }
#pragma unroll
      for (int reg = 0; reg < 4; ++reg) {
        float v = str[reg], u = atr[reg];
#pragma unroll
        for (int off = 1; off < 16; off <<= 1) {
          v += __shfl_xor(v, off);
          u += __shfl_xor(u, off);
        }
        if (rA == 0) {
          size_t r = (size_t)(row0 + wr * 64 + mi * 16 + kg * 4 + reg) * 3;
          atomicAdd(&stats[r + 1], v);
          atomicAdd(&stats[r + 2], u);
        }
      }
    }
  }
}

// ---------------- finalize: per-row loss + global sum ----------------
__global__ void finalize(const float* __restrict__ stats, const float* __restrict__ tgt,
                         const float* __restrict__ cec, const float* __restrict__ klc,
                         float* __restrict__ out) {
  __shared__ float red[16];
  int tid = threadIdx.x;  // 1024 threads
  float acc = 0.f;
  for (int r = tid; r < B_; r += 1024) {
    float ss = stats[r * 3 + 0], st = stats[r * 3 + 1], at = stats[r * 3 + 2];
    float s_lse = LN2 * __builtin_amdgcn_logf(ss);
    float t_lse = LN2 * __builtin_amdgcn_logf(st);
    float kl = s_lse - t_lse + LN2 * at / st;
    float ce = s_lse - tgt[r];
    acc += cec[r] * ce + klc[r] * kl;
  }
#pragma unroll
  for (int off = 1; off < 64; off <<= 1) acc += __shfl_xor(acc, off);
  if ((tid & 63) == 0) red[tid >> 6] = acc;
  __syncthreads();
  if (tid == 0) {
    float s = 0.f;
#pragma unroll
    for (int i = 0; i < 16; ++i) s += red[i];
    out[0] = s;
  }
}

extern "C" void kernel_launch(void* const* d_in, const int* in_sizes, int n_in,
                              void* d_out, int out_size, void* d_ws, size_t ws_size,
                              hipStream_t stream) {
  const float* sh = (const float*)d_in[0];
  const float* sc = (const float*)d_in[1];
  const float* th = (const float*)d_in[2];
  const float* tc = (const float*)d_in[3];
  const float* cec = (const float*)d_in[4];
  const float* klc = (const float*)d_in[5];
  const int* targets = (const int*)d_in[6];
  float* out = (float*)d_out;

  char* ws = (char*)d_ws;
  u8* SC8 = (u8*)ws;                               // 25,755,648
  u8* TC8 = SC8 + (size_t)V_ * D_;                 // 25,755,648
  u8* SH8 = TC8 + (size_t)V_ * D_;                 // 1,048,576
  u8* TH8 = SH8 + (size_t)B_ * D_;                 // 1,048,576
  float* stats = (float*)(TH8 + (size_t)B_ * D_);  // 24 KB
  float* tgt = stats + (size_t)B_ * 3;             // 8 KB
  // total ~53.7 MB, within the confirmed ws_size >= 55.7 MB

  hipMemsetAsync(stats, 0, (size_t)B_ * 3 * sizeof(float), stream);
  const float hscale = 16.0f * LOG2E;
  const float cscale = 16.0f;
  cast8_kernel<<<2048, 256, 0, stream>>>(sc, (uint2*)SC8, cscale, V_ * D_ / 8);
  cast8_kernel<<<2048, 256, 0, stream>>>(tc, (uint2*)TC8, cscale, V_ * D_ / 8);
  cast8_kernel<<<256, 256, 0, stream>>>(sh, (uint2*)SH8, hscale, B_ * D_ / 8);
  cast8_kernel<<<256, 256, 0, stream>>>(th, (uint2*)TH8, hscale, B_ * D_ / 8);
  tgt_kernel<<<512, 256, 0, stream>>>(sh, sc, targets, tgt);

  lce_main<<<NWG, 256, 0, stream>>>(SH8, TH8, SC8, TC8, stats);
  finalize<<<1, 1024, 0, stream>>>(stats, tgt, cec, klc, out);
}